// Round 1
// baseline (3439.347 us; speedup 1.0000x reference)
//
#include <hip/hip_runtime.h>

// SASRec forward, f32 baseline.
// Shapes: B=32,S=512,N_ITEMS=2048,E=512,H=8,L=2,DFF=2048,DK=64
// Faithful-bug: attention output only batch 0 is used (attn[0] broadcast),
// so the whole attention path is computed for batch 0 only.
// Faithful-bug 2: causal mask multiplies scores by tril (zeros, not -inf),
// BEFORE scaling; softmax runs over the full row including those zeros.

#define EDIM 512
#define SEQ 512
#define NB 32
#define NH 8
#define DKH 64
#define DFF 2048
#define NIT 2048

using f4 = float4;

// Generic tiled f32 GEMM: C[z] = act(A[z] @ B[z] + bias)
// BM,BN in {64,128}; BK=16; 256 threads; micro-tile (BM/16)x(BN/16) split in
// 4-wide groups at offsets {0,64} to keep LDS reads 2-way-max on banks.
// TRB: B is accessed transposed (B[n*ldb + k]) -- only used with BN=64.
template<int BM, int BN, int BK, int ACT, int TRB>
__global__ __launch_bounds__(256, 2)
void gemm_k(const float* __restrict__ A, int lda, long long sA,
            const float* __restrict__ Bm, int ldb, long long sB,
            const float* __restrict__ bias,
            float* __restrict__ C, int ldc, long long sC,
            int K, int causalSkip)
{
    if (causalSkip && (int)blockIdx.x * BN > (int)blockIdx.y * BM + (BM - 1)) return;
    constexpr int GA = BM / 64;          // row groups of 4
    constexpr int GB = BN / 64;          // col groups of 4
    constexpr int TM = 4 * GA, TN = 4 * GB;
    __shared__ float As[BK][BM + 4];
    __shared__ float Bs[BK][BN + 4];
    const int z = blockIdx.z;
    A  += (long long)z * sA;
    Bm += (long long)z * sB;
    C  += (long long)z * sC;
    const int row0 = blockIdx.y * BM, col0 = blockIdx.x * BN;
    const int tid = threadIdx.x;
    const int tx = tid & 15, ty = tid >> 4;
    float acc[TM][TN] = {};

    for (int kt = 0; kt < K; kt += BK) {
        // ---- A tile: BM x BK, stored transposed As[k][row] ----
        #pragma unroll
        for (int i = 0; i < GA; ++i) {
            int r  = (tid >> 2) + i * 64;
            int kk = (tid & 3) * 4;
            f4 v = *(const f4*)&A[(long long)(row0 + r) * lda + kt + kk];
            As[kk + 0][r] = v.x; As[kk + 1][r] = v.y;
            As[kk + 2][r] = v.z; As[kk + 3][r] = v.w;
        }
        // ---- B tile: BK x BN ----
        if constexpr (TRB) {
            // B[n][k] layout (e.g. K^T): read 16 consecutive k per col
            int c  = tid >> 2;
            int kk = (tid & 3) * 4;
            f4 v = *(const f4*)&Bm[(long long)(col0 + c) * ldb + kt + kk];
            Bs[kk + 0][c] = v.x; Bs[kk + 1][c] = v.y;
            Bs[kk + 2][c] = v.z; Bs[kk + 3][c] = v.w;
        } else {
            #pragma unroll
            for (int i = 0; i < (BK * BN) / 1024; ++i) {
                int idx = tid + i * 256;
                int r = idx / (BN / 4);
                int c = (idx % (BN / 4)) * 4;
                *(f4*)&Bs[r][c] = *(const f4*)&Bm[(long long)(kt + r) * ldb + col0 + c];
            }
        }
        __syncthreads();
        #pragma unroll
        for (int kk = 0; kk < BK; ++kk) {
            float a[TM], b[TN];
            #pragma unroll
            for (int g = 0; g < GA; ++g)
                *(f4*)&a[g * 4] = *(const f4*)&As[kk][ty * 4 + g * 64];
            #pragma unroll
            for (int g = 0; g < GB; ++g)
                *(f4*)&b[g * 4] = *(const f4*)&Bs[kk][tx * 4 + g * 64];
            #pragma unroll
            for (int i = 0; i < TM; ++i)
                #pragma unroll
                for (int j = 0; j < TN; ++j)
                    acc[i][j] = fmaf(a[i], b[j], acc[i][j]);
        }
        __syncthreads();
    }
    // ---- epilogue ----
    #pragma unroll
    for (int gi = 0; gi < GA; ++gi)
    #pragma unroll
    for (int ri = 0; ri < 4; ++ri) {
        int row = row0 + gi * 64 + ty * 4 + ri;
        #pragma unroll
        for (int gj = 0; gj < GB; ++gj) {
            int col = col0 + gj * 64 + tx * 4;
            f4 v;
            v.x = acc[gi * 4 + ri][gj * 4 + 0];
            v.y = acc[gi * 4 + ri][gj * 4 + 1];
            v.z = acc[gi * 4 + ri][gj * 4 + 2];
            v.w = acc[gi * 4 + ri][gj * 4 + 3];
            if (bias) {
                v.x += bias[col + 0]; v.y += bias[col + 1];
                v.z += bias[col + 2]; v.w += bias[col + 3];
            }
            if (ACT == 1) {
                v.x = fmaxf(v.x, 0.f); v.y = fmaxf(v.y, 0.f);
                v.z = fmaxf(v.z, 0.f); v.w = fmaxf(v.w, 0.f);
            }
            *(f4*)&C[(long long)row * ldc + col] = v;
        }
    }
}

// x[b,s,:] += pos_emb[s,:]   (float4 granular)
__global__ __launch_bounds__(256)
void posadd_k(float* __restrict__ x, const float* __restrict__ pos)
{
    long long i = (long long)blockIdx.x * 256 + threadIdx.x;  // float4 index
    int s = (int)((i >> 7) & 511);
    int c = (int)(i & 127) * 4;
    f4 v  = *(f4*)&x[i * 4];
    f4 pv = *(const f4*)&pos[(long long)s * 512 + c];
    v.x += pv.x; v.y += pv.y; v.z += pv.z; v.w += pv.w;
    *(f4*)&x[i * 4] = v;
}

// masked-scale softmax over one row of scores[h]: val = j<=row ? s/8 : 0,
// softmax over all 512 entries (zeros included -- faithful semantics).
__global__ __launch_bounds__(256)
void softmax_k(float* __restrict__ sc)
{
    int row = blockIdx.x, h = blockIdx.y;
    float* p = sc + ((long long)h * SEQ + row) * SEQ;
    int tid = threadIdx.x;
    int j1 = tid + 256;
    float v0 = 0.f, v1 = 0.f;
    if (tid <= row) v0 = p[tid] * 0.125f;
    if (j1  <= row) v1 = p[j1]  * 0.125f;
    float m = fmaxf(v0, v1);
    #pragma unroll
    for (int off = 32; off; off >>= 1) m = fmaxf(m, __shfl_xor(m, off));
    __shared__ float red[4];
    if ((tid & 63) == 0) red[tid >> 6] = m;
    __syncthreads();
    m = fmaxf(fmaxf(red[0], red[1]), fmaxf(red[2], red[3]));
    float e0 = __expf(v0 - m);
    float e1 = __expf(v1 - m);
    float s = e0 + e1;
    #pragma unroll
    for (int off = 32; off; off >>= 1) s += __shfl_xor(s, off);
    __syncthreads();
    if ((tid & 63) == 0) red[tid >> 6] = s;
    __syncthreads();
    s = red[0] + red[1] + red[2] + red[3];
    float inv = 1.f / s;
    p[tid] = e0 * inv;
    p[j1]  = e1 * inv;
}

// x[row,:] = LN(x[row,:] + res[row & resMask, :]) * g + b   (in place)
__global__ __launch_bounds__(128)
void addln_k(float* __restrict__ x, const float* __restrict__ res,
             unsigned resMask, const float* __restrict__ g,
             const float* __restrict__ bta)
{
    long long row = blockIdx.x;
    int tid = threadIdx.x;
    int c = tid * 4;
    f4 xv = *(f4*)&x[row * 512 + c];
    f4 rv = *(const f4*)&res[(long long)(blockIdx.x & resMask) * 512 + c];
    xv.x += rv.x; xv.y += rv.y; xv.z += rv.z; xv.w += rv.w;
    float s = xv.x + xv.y + xv.z + xv.w;
    float q = xv.x * xv.x + xv.y * xv.y + xv.z * xv.z + xv.w * xv.w;
    #pragma unroll
    for (int off = 32; off; off >>= 1) {
        s += __shfl_xor(s, off);
        q += __shfl_xor(q, off);
    }
    __shared__ float rs[2], rq[2];
    if ((tid & 63) == 0) { rs[tid >> 6] = s; rq[tid >> 6] = q; }
    __syncthreads();
    s = rs[0] + rs[1]; q = rq[0] + rq[1];
    float mean = s * (1.0f / 512.0f);
    float var  = q * (1.0f / 512.0f) - mean * mean;
    float rstd = rsqrtf(var + 1e-5f);
    f4 gv = *(const f4*)&g[c];
    f4 bv = *(const f4*)&bta[c];
    f4 o;
    o.x = (xv.x - mean) * rstd * gv.x + bv.x;
    o.y = (xv.y - mean) * rstd * gv.y + bv.y;
    o.z = (xv.z - mean) * rstd * gv.z + bv.z;
    o.w = (xv.w - mean) * rstd * gv.w + bv.w;
    *(f4*)&x[row * 512 + c] = o;
}

// out[row] = dot(x[row,:], fcW) + fcb   (one wave per row)
__global__ __launch_bounds__(256)
void fc_k(const float* __restrict__ x, const float* __restrict__ w,
          const float* __restrict__ bb, float* __restrict__ out)
{
    int row  = blockIdx.x * 4 + (threadIdx.x >> 6);
    int lane = threadIdx.x & 63;
    const float* xr = x + (long long)row * 512;
    f4 a0 = *(const f4*)&xr[lane * 8];
    f4 a1 = *(const f4*)&xr[lane * 8 + 4];
    f4 w0 = *(const f4*)&w[lane * 8];
    f4 w1 = *(const f4*)&w[lane * 8 + 4];
    float s = a0.x * w0.x + a0.y * w0.y + a0.z * w0.z + a0.w * w0.w
            + a1.x * w1.x + a1.y * w1.y + a1.z * w1.z + a1.w * w1.w;
    #pragma unroll
    for (int off = 32; off; off >>= 1) s += __shfl_xor(s, off);
    if (lane == 0) out[row] = s + bb[0];
}

extern "C" void kernel_launch(void* const* d_in, const int* in_sizes, int n_in,
                              void* d_out, int out_size, void* d_ws, size_t ws_size,
                              hipStream_t stream)
{
    const float* input_seq = (const float*)d_in[0];
    const float* emb_W  = (const float*)d_in[1];
    const float* emb_b  = (const float*)d_in[2];
    const float* pos_emb= (const float*)d_in[3];
    const float* Wq = (const float*)d_in[4];
    const float* bq = (const float*)d_in[5];
    const float* Wk = (const float*)d_in[6];
    const float* bk = (const float*)d_in[7];
    const float* Wv = (const float*)d_in[8];
    const float* bv = (const float*)d_in[9];
    const float* Wo = (const float*)d_in[10];
    const float* bo = (const float*)d_in[11];
    const float* ln1_g = (const float*)d_in[12];
    const float* ln1_b = (const float*)d_in[13];
    const float* W1 = (const float*)d_in[14];
    const float* b1 = (const float*)d_in[15];
    const float* W2 = (const float*)d_in[16];
    const float* b2 = (const float*)d_in[17];
    const float* ln2_g = (const float*)d_in[18];
    const float* ln2_b = (const float*)d_in[19];
    const float* fcW = (const float*)d_in[20];
    const float* fcb = (const float*)d_in[21];
    float* out = (float*)d_out;

    // workspace layout (floats); total ~89 MB
    float* ws       = (float*)d_ws;
    float* xbuf     = ws;                      // 16384 x 512
    float* q0       = xbuf + 8388608;          // 512 x 512
    float* k0       = q0 + 262144;
    float* v0       = k0 + 262144;
    float* scores   = v0 + 262144;             // 8 x 512 x 512
    float* attn0    = scores + 2097152;        // 512 x 512 (heads concat)
    float* attnout0 = attn0 + 262144;          // 512 x 512
    float* hidden   = attnout0 + 262144;       // 4096 x 2048 (8-batch chunk)
    float* ffout    = hidden + 8388608;        // 4096 x 512

    const int M = NB * SEQ;  // 16384
    dim3 blk(256);

    // 1) x = input_seq @ emb_W + emb_b ; x += pos_emb
    gemm_k<128,128,16,0,0><<<dim3(EDIM/128, M/128, 1), blk, 0, stream>>>(
        input_seq, NIT, 0, emb_W, EDIM, 0, emb_b, xbuf, EDIM, 0, NIT, 0);
    posadd_k<<<dim3((M * EDIM / 4) / 256), blk, 0, stream>>>(xbuf, pos_emb);

    for (int l = 0; l < 2; ++l) {
        const float* Wql = Wq + (long long)l * EDIM * EDIM;
        const float* Wkl = Wk + (long long)l * EDIM * EDIM;
        const float* Wvl = Wv + (long long)l * EDIM * EDIM;
        const float* Wol = Wo + (long long)l * EDIM * EDIM;
        const float* W1l = W1 + (long long)l * EDIM * DFF;
        const float* W2l = W2 + (long long)l * DFF * EDIM;
        const float* bql = bq + l * EDIM;
        const float* bkl = bk + l * EDIM;
        const float* bvl = bv + l * EDIM;
        const float* bol = bo + l * EDIM;
        const float* b1l = b1 + l * DFF;
        const float* b2l = b2 + l * EDIM;

        // --- attention path: batch 0 only (attn[0] broadcast bug) ---
        gemm_k<64,64,16,0,0><<<dim3(8, 8, 1), blk, 0, stream>>>(
            xbuf, EDIM, 0, Wql, EDIM, 0, bql, q0, EDIM, 0, EDIM, 0);
        gemm_k<64,64,16,0,0><<<dim3(8, 8, 1), blk, 0, stream>>>(
            xbuf, EDIM, 0, Wkl, EDIM, 0, bkl, k0, EDIM, 0, EDIM, 0);
        gemm_k<64,64,16,0,0><<<dim3(8, 8, 1), blk, 0, stream>>>(
            xbuf, EDIM, 0, Wvl, EDIM, 0, bvl, v0, EDIM, 0, EDIM, 0);
        // scores[h] = q0_h @ k0_h^T  (skip fully-masked upper tiles)
        gemm_k<64,64,16,0,1><<<dim3(8, 8, NH), blk, 0, stream>>>(
            q0, EDIM, DKH, k0, EDIM, DKH, nullptr,
            scores, SEQ, (long long)SEQ * SEQ, DKH, 1);
        softmax_k<<<dim3(SEQ, NH), blk, 0, stream>>>(scores);
        // attn0[:, h*64:] = probs[h] @ v0_h
        gemm_k<64,64,16,0,0><<<dim3(1, 8, NH), blk, 0, stream>>>(
            scores, SEQ, (long long)SEQ * SEQ, v0, EDIM, DKH, nullptr,
            attn0, EDIM, DKH, SEQ, 0);
        // attnout0 = attn0 @ Wo + bo
        gemm_k<64,64,16,0,0><<<dim3(8, 8, 1), blk, 0, stream>>>(
            attn0, EDIM, 0, Wol, EDIM, 0, bol, attnout0, EDIM, 0, EDIM, 0);
        // x = LN1(x + attnout0[s])  broadcast over batches
        addln_k<<<dim3(M), dim3(128), 0, stream>>>(
            xbuf, attnout0, 511u, ln1_g + l * EDIM, ln1_b + l * EDIM);

        // --- FFN, chunked 8 batches (4096 rows) at a time ---
        for (int cch = 0; cch < 4; ++cch) {
            float* xc = xbuf + (long long)cch * 4096 * EDIM;
            gemm_k<128,128,16,1,0><<<dim3(DFF/128, 4096/128, 1), blk, 0, stream>>>(
                xc, EDIM, 0, W1l, DFF, 0, b1l, hidden, DFF, 0, EDIM, 0);
            gemm_k<128,64,16,0,0><<<dim3(EDIM/64, 4096/128, 1), blk, 0, stream>>>(
                hidden, DFF, 0, W2l, EDIM, 0, b2l, ffout, EDIM, 0, DFF, 0);
            addln_k<<<dim3(4096), dim3(128), 0, stream>>>(
                xc, ffout, 0x7fffffffu, ln2_g + l * EDIM, ln2_b + l * EDIM);
        }
    }

    // 3) out = x @ fc_W + fc_b
    fc_k<<<dim3(M / 4), blk, 0, stream>>>(xbuf, fcW, fcb, out);
}

// Round 2
// 583.339 us; speedup vs baseline: 5.8960x; 5.8960x over previous
//
#include <hip/hip_runtime.h>

// SASRec forward, bf16-MFMA version (m97-style 128x128 tile, BK=32,
// global_load_lds staging, XOR chunk-swizzle, 2-barrier K-loop).
// Faithful-bug 1: attention computed for batch 0 only (attn[0] broadcast).
// Faithful-bug 2: tril-then-scale with zeros (not -inf); softmax over full row.

typedef __bf16 bf16;
typedef __bf16 bf16x8 __attribute__((ext_vector_type(8)));
typedef __bf16 bf16x4 __attribute__((ext_vector_type(4)));
typedef float  f32x4  __attribute__((ext_vector_type(4)));

#define EDIM 512
#define SEQ 512
#define NB 32
#define NH 8
#define DFFD 2048
#define NIT 2048

__device__ __forceinline__ void gl2lds16(const bf16* g, void* l) {
    __builtin_amdgcn_global_load_lds(
        (const __attribute__((address_space(1))) void*)g,
        (__attribute__((address_space(3))) void*)l, 16, 0, 0);
}

// C = act(A @ Bt^T + bias [+pos]) ; Bt is [N][K] (B transposed), bf16.
// A: bf16 [M][K] (AF32=0) or f32 [M][K] converted in-flight (AF32=1).
// CMODE: 0 = f32 out, 1 = bf16 out, 2 = both. POS: add pos_emb[(row&511)][col].
template<int BM, int BN, int ACT, int CMODE, int POS, int AF32, int CAUSAL>
__global__ __launch_bounds__(256, 2)
void mgemm(const void* __restrict__ Aq, int lda, long long sA,
           const bf16* __restrict__ Bt, int ldb, long long sB,
           const float* __restrict__ bias, const float* __restrict__ pos,
           float* __restrict__ Cf, bf16* __restrict__ Cb, int ldc, long long sC,
           int K)
{
    static_assert(BM == 128 && (BN == 128 || BN == 64), "tile");
    if (CAUSAL && (int)blockIdx.x * BN > (int)blockIdx.y * BM + (BM - 1)) return;
    constexpr int TM = BM / 32, TN = BN / 32;
    __shared__ bf16 As[BM * 32];
    __shared__ bf16 Bs[BN * 32];
    char* AsB = (char*)As;
    char* BsB = (char*)Bs;
    const int tid = threadIdx.x;
    const int lane = tid & 63, wv = tid >> 6;
    const int wr = wv >> 1, wc = wv & 1;
    const int fr = lane & 15, fc = lane >> 4;
    const int row0 = blockIdx.y * BM, col0 = blockIdx.x * BN;
    const int z = blockIdx.z;

    const bf16*  Ab = (const bf16*)Aq  + (long long)z * sA;
    const float* Af = (const float*)Aq + (long long)z * sA;
    Bt += (long long)z * sB;
    if constexpr (CMODE == 0 || CMODE == 2) Cf += (long long)z * sC;
    if constexpr (CMODE >= 1)               Cb += (long long)z * sC;

    f32x4 acc[TM][TN] = {};

    // ---- staging address precompute ----
    constexpr int AIT = BM / 64;   // 16B chunks per thread for A tile
    constexpr int BIT = BN / 64;
    const bf16* aSrc[AIT];
    const float* aFsrc[AIT];
    int dOffA[AIT];
    #pragma unroll
    for (int it = 0; it < AIT; ++it) {
        int cL = it * 256 + tid;
        int row = cL >> 2, ch = cL & 3;
        if constexpr (AF32) {
            aFsrc[it] = Af + (row0 + row) * lda + ch * 8;
            dOffA[it] = row * 64 + ((ch ^ (row & 3)) * 16);
        } else {
            aSrc[it] = Ab + (long long)(row0 + row) * lda + ((ch ^ (row & 3)) * 8);
        }
    }
    const bf16* bSrc[BIT];
    #pragma unroll
    for (int it = 0; it < BIT; ++it) {
        int cL = it * 256 + tid;
        int row = cL >> 2, ch = cL & 3;
        bSrc[it] = Bt + (long long)(col0 + row) * ldb + ((ch ^ (row & 3)) * 8);
    }
    // ---- fragment LDS offsets ----
    int aOff[TM], bOff[TN];
    #pragma unroll
    for (int m = 0; m < TM; ++m) {
        int row = wr * (BM / 2) + m * 16 + fr;
        aOff[m] = row * 64 + ((fc ^ (row & 3)) * 16);
    }
    #pragma unroll
    for (int n = 0; n < TN; ++n) {
        int row = wc * (BN / 2) + n * 16 + fr;
        bOff[n] = row * 64 + ((fc ^ (row & 3)) * 16);
    }

    for (int kt = 0; kt < K; kt += 32) {
        if constexpr (AF32) {
            #pragma unroll
            for (int it = 0; it < AIT; ++it) {
                const float* s = aFsrc[it] + kt;
                float4 u = *(const float4*)s;
                float4 v2 = *(const float4*)(s + 4);
                bf16x8 w;
                w[0] = (bf16)u.x;  w[1] = (bf16)u.y;
                w[2] = (bf16)u.z;  w[3] = (bf16)u.w;
                w[4] = (bf16)v2.x; w[5] = (bf16)v2.y;
                w[6] = (bf16)v2.z; w[7] = (bf16)v2.w;
                *(bf16x8*)(AsB + dOffA[it]) = w;
            }
        } else {
            #pragma unroll
            for (int it = 0; it < AIT; ++it)
                gl2lds16(aSrc[it] + kt, AsB + it * 4096 + wv * 1024);
        }
        #pragma unroll
        for (int it = 0; it < BIT; ++it)
            gl2lds16(bSrc[it] + kt, BsB + it * 4096 + wv * 1024);
        __syncthreads();
        bf16x8 a[TM], b[TN];
        #pragma unroll
        for (int m = 0; m < TM; ++m) a[m] = *(const bf16x8*)(AsB + aOff[m]);
        #pragma unroll
        for (int n = 0; n < TN; ++n) b[n] = *(const bf16x8*)(BsB + bOff[n]);
        #pragma unroll
        for (int m = 0; m < TM; ++m)
            #pragma unroll
            for (int n = 0; n < TN; ++n)
                acc[m][n] = __builtin_amdgcn_mfma_f32_16x16x32_bf16(a[m], b[n], acc[m][n], 0, 0, 0);
        __syncthreads();
    }

    // ---- epilogue ----
    #pragma unroll
    for (int n = 0; n < TN; ++n) {
        int col = col0 + wc * (BN / 2) + n * 16 + fr;
        float bb = bias ? bias[col] : 0.f;
        #pragma unroll
        for (int m = 0; m < TM; ++m) {
            int rbase = row0 + wr * (BM / 2) + m * 16 + fc * 4;
            #pragma unroll
            for (int r = 0; r < 4; ++r) {
                float x = acc[m][n][r] + bb;
                if constexpr (POS) x += pos[((rbase + r) & 511) * 512 + col];
                if constexpr (ACT) x = fmaxf(x, 0.f);
                long long ci = (long long)(rbase + r) * ldc + col;
                if constexpr (CMODE == 0 || CMODE == 2) Cf[ci] = x;
                if constexpr (CMODE >= 1)               Cb[ci] = (bf16)x;
            }
        }
    }
}

// W [K][N] f32  ->  WT [N][K] bf16   (32x32 LDS tiles)
__global__ __launch_bounds__(256)
void wt_k(const float* __restrict__ W, bf16* __restrict__ WT, int K, int N)
{
    __shared__ float t[32][33];
    int n0 = blockIdx.x * 32, k0 = blockIdx.y * 32;
    int r = threadIdx.x >> 3, c4 = (threadIdx.x & 7) * 4;
    float4 v = *(const float4*)&W[(long long)(k0 + r) * N + n0 + c4];
    t[r][c4 + 0] = v.x; t[r][c4 + 1] = v.y;
    t[r][c4 + 2] = v.z; t[r][c4 + 3] = v.w;
    __syncthreads();
    int n = threadIdx.x >> 3, kk4 = (threadIdx.x & 7) * 4;
    bf16x4 o;
    o[0] = (bf16)t[kk4 + 0][n]; o[1] = (bf16)t[kk4 + 1][n];
    o[2] = (bf16)t[kk4 + 2][n]; o[3] = (bf16)t[kk4 + 3][n];
    *(bf16x4*)&WT[(long long)(n0 + n) * K + k0 + kk4] = o;
}

// pack bq|bk|bv -> qkvB[2][1536]
__global__ __launch_bounds__(512)
void packb_k(const float* __restrict__ bq, const float* __restrict__ bk,
             const float* __restrict__ bv, float* __restrict__ dst)
{
    int l = blockIdx.x, t = threadIdx.x;
    dst[l * 1536 + t]        = bq[l * 512 + t];
    dst[l * 1536 + 512 + t]  = bk[l * 512 + t];
    dst[l * 1536 + 1024 + t] = bv[l * 512 + t];
}

// VT[h][d][s] = qkv[s][1024 + h*64 + d]   (bf16 64x64 LDS transpose)
__global__ __launch_bounds__(256)
void vt_k(const bf16* __restrict__ qkv, bf16* __restrict__ VT)
{
    __shared__ bf16 t[64][80];
    int h = blockIdx.y, s0 = blockIdx.x * 64;
    int r = threadIdx.x >> 2, c16 = (threadIdx.x & 3) * 16;
    const bf16* src = qkv + (long long)(s0 + r) * 1536 + 1024 + h * 64 + c16;
    *(bf16x8*)&t[r][c16]     = *(const bf16x8*)src;
    *(bf16x8*)&t[r][c16 + 8] = *(const bf16x8*)(src + 8);
    __syncthreads();
    int d = r, seg = c16;
    bf16 tmp[16];
    #pragma unroll
    for (int j = 0; j < 16; ++j) tmp[j] = t[seg + j][d];
    bf16* dst = VT + ((long long)(h * 64 + d)) * 512 + s0 + seg;
    *(bf16x8*)dst       = *(bf16x8*)&tmp[0];
    *(bf16x8*)(dst + 8) = *(bf16x8*)&tmp[8];
}

// masked-scale softmax: f32 scores in, bf16 probs out (full row incl. masked)
__global__ __launch_bounds__(256)
void softmax_k(const float* __restrict__ sc, bf16* __restrict__ pr)
{
    int row = blockIdx.x, h = blockIdx.y;
    const float* p = sc + ((long long)(h * SEQ + row)) * SEQ;
    bf16* o = pr + ((long long)(h * SEQ + row)) * SEQ;
    int tid = threadIdx.x;
    int j1 = tid + 256;
    float v0 = 0.f, v1 = 0.f;
    if (tid <= row) v0 = p[tid] * 0.125f;
    if (j1  <= row) v1 = p[j1]  * 0.125f;
    float m = fmaxf(v0, v1);
    #pragma unroll
    for (int off = 32; off; off >>= 1) m = fmaxf(m, __shfl_xor(m, off));
    __shared__ float red[4];
    if ((tid & 63) == 0) red[tid >> 6] = m;
    __syncthreads();
    m = fmaxf(fmaxf(red[0], red[1]), fmaxf(red[2], red[3]));
    float e0 = __expf(v0 - m);
    float e1 = __expf(v1 - m);
    float s = e0 + e1;
    #pragma unroll
    for (int off = 32; off; off >>= 1) s += __shfl_xor(s, off);
    __syncthreads();
    if ((tid & 63) == 0) red[tid >> 6] = s;
    __syncthreads();
    s = red[0] + red[1] + red[2] + red[3];
    float inv = 1.f / s;
    o[tid] = (bf16)(e0 * inv);
    o[j1]  = (bf16)(e1 * inv);
}

// x[row] = LN(x[row] + res[row & mask]) ; writes f32 x and bf16 xb
__global__ __launch_bounds__(128)
void addln_k(float* __restrict__ x, bf16* __restrict__ xb,
             const float* __restrict__ res, unsigned resMask,
             const float* __restrict__ g, const float* __restrict__ bta)
{
    long long row = blockIdx.x;
    int tid = threadIdx.x;
    int c = tid * 4;
    float4 xv = *(float4*)&x[row * 512 + c];
    float4 rv = *(const float4*)&res[(long long)(blockIdx.x & resMask) * 512 + c];
    xv.x += rv.x; xv.y += rv.y; xv.z += rv.z; xv.w += rv.w;
    float s = xv.x + xv.y + xv.z + xv.w;
    float q = xv.x * xv.x + xv.y * xv.y + xv.z * xv.z + xv.w * xv.w;
    #pragma unroll
    for (int off = 32; off; off >>= 1) {
        s += __shfl_xor(s, off);
        q += __shfl_xor(q, off);
    }
    __shared__ float rs[2], rq[2];
    if ((tid & 63) == 0) { rs[tid >> 6] = s; rq[tid >> 6] = q; }
    __syncthreads();
    s = rs[0] + rs[1]; q = rq[0] + rq[1];
    float mean = s * (1.0f / 512.0f);
    float var  = q * (1.0f / 512.0f) - mean * mean;
    float rstd = rsqrtf(var + 1e-5f);
    float4 gv = *(const float4*)&g[c];
    float4 bv = *(const float4*)&bta[c];
    float4 o;
    o.x = (xv.x - mean) * rstd * gv.x + bv.x;
    o.y = (xv.y - mean) * rstd * gv.y + bv.y;
    o.z = (xv.z - mean) * rstd * gv.z + bv.z;
    o.w = (xv.w - mean) * rstd * gv.w + bv.w;
    *(float4*)&x[row * 512 + c] = o;
    bf16* xo = xb + row * 512 + c;
    xo[0] = (bf16)o.x; xo[1] = (bf16)o.y; xo[2] = (bf16)o.z; xo[3] = (bf16)o.w;
}

// out[row] = dot(x[row,:], fcW) + fcb
__global__ __launch_bounds__(256)
void fc_k(const float* __restrict__ x, const float* __restrict__ w,
          const float* __restrict__ bb, float* __restrict__ out)
{
    int row  = blockIdx.x * 4 + (threadIdx.x >> 6);
    int lane = threadIdx.x & 63;
    const float* xr = x + (long long)row * 512;
    float4 a0 = *(const float4*)&xr[lane * 8];
    float4 a1 = *(const float4*)&xr[lane * 8 + 4];
    float4 w0 = *(const float4*)&w[lane * 8];
    float4 w1 = *(const float4*)&w[lane * 8 + 4];
    float s = a0.x * w0.x + a0.y * w0.y + a0.z * w0.z + a0.w * w0.w
            + a1.x * w1.x + a1.y * w1.y + a1.z * w1.z + a1.w * w1.w;
    #pragma unroll
    for (int off = 32; off; off >>= 1) s += __shfl_xor(s, off);
    if (lane == 0) out[row] = s + bb[0];
}

extern "C" void kernel_launch(void* const* d_in, const int* in_sizes, int n_in,
                              void* d_out, int out_size, void* d_ws, size_t ws_size,
                              hipStream_t stream)
{
    const float* input_seq = (const float*)d_in[0];
    const float* emb_W  = (const float*)d_in[1];
    const float* emb_b  = (const float*)d_in[2];
    const float* pos_emb= (const float*)d_in[3];
    const float* Wq = (const float*)d_in[4];
    const float* bq = (const float*)d_in[5];
    const float* Wk = (const float*)d_in[6];
    const float* bk = (const float*)d_in[7];
    const float* Wv = (const float*)d_in[8];
    const float* bv = (const float*)d_in[9];
    const float* Wo = (const float*)d_in[10];
    const float* bo = (const float*)d_in[11];
    const float* ln1_g = (const float*)d_in[12];
    const float* ln1_b = (const float*)d_in[13];
    const float* W1 = (const float*)d_in[14];
    const float* b1 = (const float*)d_in[15];
    const float* W2 = (const float*)d_in[16];
    const float* b2 = (const float*)d_in[17];
    const float* ln2_g = (const float*)d_in[18];
    const float* ln2_b = (const float*)d_in[19];
    const float* fcW = (const float*)d_in[20];
    const float* fcb = (const float*)d_in[21];
    float* out = (float*)d_out;

    // ---- workspace layout ----
    char* w = (char*)d_ws;
    size_t off = 0;
    auto alloc = [&](size_t b) -> void* {
        off = (off + 255) & ~(size_t)255;
        void* p = w + off;
        off += b;
        return p;
    };
    float* xbuf   = (float*)alloc(16384ull * 512 * 4);   // 32 MB
    bf16*  xb     = (bf16*) alloc(16384ull * 512 * 2);   // 16 MB
    bf16*  embWT  = (bf16*) alloc(512ull * 2048 * 2);
    bf16*  qkvWT  = (bf16*) alloc(2ull * 1536 * 512 * 2);
    bf16*  WoT    = (bf16*) alloc(2ull * 512 * 512 * 2);
    bf16*  W1T    = (bf16*) alloc(2ull * 2048 * 512 * 2);
    bf16*  W2T    = (bf16*) alloc(2ull * 512 * 2048 * 2);
    float* qkvB   = (float*)alloc(2ull * 1536 * 4);
    off = (off + 255) & ~(size_t)255;
    size_t dyn0 = off;
    char* dynp = w + dyn0;
    // attention overlay (16.25 MB)
    bf16*  qkv      = (bf16*)dynp;                         // 512x1536
    float* scores   = (float*)(dynp + 1572864);            // 8x512x512 f32
    bf16*  probs    = (bf16*)(dynp + 1572864 + 8388608);   // 8x512x512 bf16
    bf16*  VT       = (bf16*)(dynp + 1572864 + 8388608 + 4194304);
    bf16*  attn0b   = (bf16*)(dynp + 1572864 + 8388608 + 4194304 + 524288);
    float* attnout0 = (float*)(dynp + 1572864 + 8388608 + 4194304 + 524288 + 524288);
    // FFN overlay (same region): hidden bf16 [R][2048] + ffout f32 [R][512]
    size_t dynbytes = ws_size > dyn0 ? ws_size - dyn0 : 0;
    long long Rll = (long long)(dynbytes / 6144) & ~127ll;
    int R = (int)(Rll > 16384 ? 16384 : Rll);
    if (R < 128) R = 128;
    bf16*  hidden = (bf16*)dynp;
    float* ffout  = (float*)(dynp + (size_t)R * 4096);

    dim3 blk(256);

    // ---- weight conversion (transposed bf16) ----
    wt_k<<<dim3(16, 64), blk, 0, stream>>>(emb_W, embWT, 2048, 512);
    for (int l = 0; l < 2; ++l) {
        wt_k<<<dim3(16, 16), blk, 0, stream>>>(Wq + l * 262144, qkvWT + l * 786432,          512, 512);
        wt_k<<<dim3(16, 16), blk, 0, stream>>>(Wk + l * 262144, qkvWT + l * 786432 + 262144, 512, 512);
        wt_k<<<dim3(16, 16), blk, 0, stream>>>(Wv + l * 262144, qkvWT + l * 786432 + 524288, 512, 512);
        wt_k<<<dim3(16, 16), blk, 0, stream>>>(Wo + l * 262144, WoT + l * 262144, 512, 512);
        wt_k<<<dim3(64, 16), blk, 0, stream>>>(W1 + l * 1048576, W1T + l * 1048576, 512, 2048);
        wt_k<<<dim3(16, 64), blk, 0, stream>>>(W2 + l * 1048576, W2T + l * 1048576, 2048, 512);
    }
    packb_k<<<dim3(2), dim3(512), 0, stream>>>(bq, bk, bv, qkvB);

    // ---- embedding: x = input_seq @ emb_W + emb_b + pos_emb ; dual-write ----
    mgemm<128, 128, 0, 2, 1, 1, 0><<<dim3(4, 128), blk, 0, stream>>>(
        input_seq, 2048, 0, embWT, 2048, 0, emb_b, pos_emb,
        xbuf, xb, 512, 0, 2048);

    for (int l = 0; l < 2; ++l) {
        const bf16* qkvWT_l = qkvWT + l * 786432;
        const bf16* WoT_l   = WoT + l * 262144;
        const bf16* W1T_l   = W1T + l * 1048576;
        const bf16* W2T_l   = W2T + l * 1048576;

        // QKV projection (batch 0 rows only), packed N=1536, bf16 out
        mgemm<128, 128, 0, 1, 0, 0, 0><<<dim3(12, 4), blk, 0, stream>>>(
            xb, 512, 0, qkvWT_l, 512, 0, qkvB + l * 1536, nullptr,
            nullptr, qkv, 1536, 0, 512);
        // scores[h] = Qh @ Kh^T (causal tile skip), f32 out
        mgemm<128, 128, 0, 0, 0, 0, 1><<<dim3(4, 4, 8), blk, 0, stream>>>(
            qkv, 1536, 64, qkv + 512, 1536, 64, nullptr, nullptr,
            scores, nullptr, 512, 262144, 64);
        softmax_k<<<dim3(512, 8), blk, 0, stream>>>(scores, probs);
        vt_k<<<dim3(8, 8), blk, 0, stream>>>(qkv, VT);
        // attn0 = probs @ V (per head, N=64), bf16 out
        mgemm<128, 64, 0, 1, 0, 0, 0><<<dim3(1, 4, 8), blk, 0, stream>>>(
            probs, 512, 262144, VT, 512, 32768, nullptr, nullptr,
            nullptr, attn0b, 512, 64, 512);
        // attnout0 = attn0 @ Wo + bo, f32 out
        mgemm<128, 128, 0, 0, 0, 0, 0><<<dim3(4, 4), blk, 0, stream>>>(
            attn0b, 512, 0, WoT_l, 512, 0, bo + l * 512, nullptr,
            attnout0, nullptr, 512, 0, 512);
        // x = LN1(x + attnout0[s]) broadcast
        addln_k<<<dim3(16384), dim3(128), 0, stream>>>(
            xbuf, xb, attnout0, 511u, ln1_g + l * 512, ln1_b + l * 512);

        // ---- FFN, chunked by R rows ----
        for (int r0 = 0; r0 < 16384; r0 += R) {
            int Mc = 16384 - r0 < R ? 16384 - r0 : R;
            mgemm<128, 128, 1, 1, 0, 0, 0><<<dim3(16, Mc / 128), blk, 0, stream>>>(
                xb + (long long)r0 * 512, 512, 0, W1T_l, 512, 0, b1 + l * 2048,
                nullptr, nullptr, hidden, 2048, 0, 512);
            if ((Mc / 128) * 4 >= 224) {
                mgemm<128, 128, 0, 0, 0, 0, 0><<<dim3(4, Mc / 128), blk, 0, stream>>>(
                    hidden, 2048, 0, W2T_l, 2048, 0, b2 + l * 512, nullptr,
                    ffout, nullptr, 512, 0, 2048);
            } else {
                mgemm<128, 64, 0, 0, 0, 0, 0><<<dim3(8, Mc / 128), blk, 0, stream>>>(
                    hidden, 2048, 0, W2T_l, 2048, 0, b2 + l * 512, nullptr,
                    ffout, nullptr, 512, 0, 2048);
            }
            addln_k<<<dim3(Mc), dim3(128), 0, stream>>>(
                xbuf + (long long)r0 * 512, xb + (long long)r0 * 512, ffout,
                0xffffffffu, ln2_g + l * 512, ln2_b + l * 512);
        }
    }

    // ---- out = x @ fc_W + fc_b ----
    fc_k<<<dim3(4096), blk, 0, stream>>>(xbuf, fcW, fcb, out);
}

// Round 3
// 496.746 us; speedup vs baseline: 6.9237x; 1.1743x over previous
//
#include <hip/hip_runtime.h>

// SASRec forward, bf16-MFMA version (m97-style 128x128 tile, BK=32,
// global_load_lds staging, XOR chunk-swizzle, 2-barrier K-loop).
// Round 2: + bijective XCD-aware block swizzle (m204) in mgemm for L2 reuse.
// Faithful-bug 1: attention computed for batch 0 only (attn[0] broadcast).
// Faithful-bug 2: tril-then-scale with zeros (not -inf); softmax over full row.

typedef __bf16 bf16;
typedef __bf16 bf16x8 __attribute__((ext_vector_type(8)));
typedef __bf16 bf16x4 __attribute__((ext_vector_type(4)));
typedef float  f32x4  __attribute__((ext_vector_type(4)));

#define EDIM 512
#define SEQ 512
#define NB 32
#define NH 8
#define DFFD 2048
#define NIT 2048

__device__ __forceinline__ void gl2lds16(const bf16* g, void* l) {
    __builtin_amdgcn_global_load_lds(
        (const __attribute__((address_space(1))) void*)g,
        (__attribute__((address_space(3))) void*)l, 16, 0, 0);
}

// C = act(A @ Bt^T + bias [+pos]) ; Bt is [N][K] (B transposed), bf16.
// A: bf16 [M][K] (AF32=0) or f32 [M][K] converted in-flight (AF32=1).
// CMODE: 0 = f32 out, 1 = bf16 out, 2 = both. POS: add pos_emb[(row&511)][col].
template<int BM, int BN, int ACT, int CMODE, int POS, int AF32, int CAUSAL>
__global__ __launch_bounds__(256, 2)
void mgemm(const void* __restrict__ Aq, int lda, long long sA,
           const bf16* __restrict__ Bt, int ldb, long long sB,
           const float* __restrict__ bias, const float* __restrict__ pos,
           float* __restrict__ Cf, bf16* __restrict__ Cb, int ldc, long long sC,
           int K)
{
    static_assert(BM == 128 && (BN == 128 || BN == 64), "tile");
    // ---- bijective XCD swizzle (m204): each XCD gets a contiguous
    // row-major chunk -> blocks sharing an A row-panel stay on one L2 ----
    const int gx = gridDim.x, gy = gridDim.y;
    const int nwg = gx * gy;
    const int b = blockIdx.y * gx + blockIdx.x;
    const int q = nwg >> 3, r = nwg & 7;
    const int xcd = b & 7, loc = b >> 3;
    const int wg = (xcd < r ? xcd * (q + 1) : r * (q + 1) + (xcd - r) * q) + loc;
    const int bx = wg % gx, by = wg / gx;

    if (CAUSAL && bx * BN > by * BM + (BM - 1)) return;
    constexpr int TM = BM / 32, TN = BN / 32;
    __shared__ bf16 As[BM * 32];
    __shared__ bf16 Bs[BN * 32];
    char* AsB = (char*)As;
    char* BsB = (char*)Bs;
    const int tid = threadIdx.x;
    const int lane = tid & 63, wv = tid >> 6;
    const int wr = wv >> 1, wc = wv & 1;
    const int fr = lane & 15, fc = lane >> 4;
    const int row0 = by * BM, col0 = bx * BN;
    const int z = blockIdx.z;

    const bf16*  Ab = (const bf16*)Aq  + (long long)z * sA;
    const float* Af = (const float*)Aq + (long long)z * sA;
    Bt += (long long)z * sB;
    if constexpr (CMODE == 0 || CMODE == 2) Cf += (long long)z * sC;
    if constexpr (CMODE >= 1)               Cb += (long long)z * sC;

    f32x4 acc[TM][TN] = {};

    // ---- staging address precompute ----
    constexpr int AIT = BM / 64;   // 16B chunks per thread for A tile
    constexpr int BIT = BN / 64;
    const bf16* aSrc[AIT];
    const float* aFsrc[AIT];
    int dOffA[AIT];
    #pragma unroll
    for (int it = 0; it < AIT; ++it) {
        int cL = it * 256 + tid;
        int row = cL >> 2, ch = cL & 3;
        if constexpr (AF32) {
            aFsrc[it] = Af + (row0 + row) * lda + ch * 8;
            dOffA[it] = row * 64 + ((ch ^ (row & 3)) * 16);
        } else {
            aSrc[it] = Ab + (long long)(row0 + row) * lda + ((ch ^ (row & 3)) * 8);
        }
    }
    const bf16* bSrc[BIT];
    #pragma unroll
    for (int it = 0; it < BIT; ++it) {
        int cL = it * 256 + tid;
        int row = cL >> 2, ch = cL & 3;
        bSrc[it] = Bt + (long long)(col0 + row) * ldb + ((ch ^ (row & 3)) * 8);
    }
    // ---- fragment LDS offsets ----
    int aOff[TM], bOff[TN];
    #pragma unroll
    for (int m = 0; m < TM; ++m) {
        int row = wr * (BM / 2) + m * 16 + fr;
        aOff[m] = row * 64 + ((fc ^ (row & 3)) * 16);
    }
    #pragma unroll
    for (int n = 0; n < TN; ++n) {
        int row = wc * (BN / 2) + n * 16 + fr;
        bOff[n] = row * 64 + ((fc ^ (row & 3)) * 16);
    }

    for (int kt = 0; kt < K; kt += 32) {
        if constexpr (AF32) {
            #pragma unroll
            for (int it = 0; it < AIT; ++it) {
                const float* s = aFsrc[it] + kt;
                float4 u = *(const float4*)s;
                float4 v2 = *(const float4*)(s + 4);
                bf16x8 w;
                w[0] = (bf16)u.x;  w[1] = (bf16)u.y;
                w[2] = (bf16)u.z;  w[3] = (bf16)u.w;
                w[4] = (bf16)v2.x; w[5] = (bf16)v2.y;
                w[6] = (bf16)v2.z; w[7] = (bf16)v2.w;
                *(bf16x8*)(AsB + dOffA[it]) = w;
            }
        } else {
            #pragma unroll
            for (int it = 0; it < AIT; ++it)
                gl2lds16(aSrc[it] + kt, AsB + it * 4096 + wv * 1024);
        }
        #pragma unroll
        for (int it = 0; it < BIT; ++it)
            gl2lds16(bSrc[it] + kt, BsB + it * 4096 + wv * 1024);
        __syncthreads();
        bf16x8 a[TM], b2[TN];
        #pragma unroll
        for (int m = 0; m < TM; ++m) a[m] = *(const bf16x8*)(AsB + aOff[m]);
        #pragma unroll
        for (int n = 0; n < TN; ++n) b2[n] = *(const bf16x8*)(BsB + bOff[n]);
        #pragma unroll
        for (int m = 0; m < TM; ++m)
            #pragma unroll
            for (int n = 0; n < TN; ++n)
                acc[m][n] = __builtin_amdgcn_mfma_f32_16x16x32_bf16(a[m], b2[n], acc[m][n], 0, 0, 0);
        __syncthreads();
    }

    // ---- epilogue ----
    #pragma unroll
    for (int n = 0; n < TN; ++n) {
        int col = col0 + wc * (BN / 2) + n * 16 + fr;
        float bb = bias ? bias[col] : 0.f;
        #pragma unroll
        for (int m = 0; m < TM; ++m) {
            int rbase = row0 + wr * (BM / 2) + m * 16 + fc * 4;
            #pragma unroll
            for (int rr = 0; rr < 4; ++rr) {
                float x = acc[m][n][rr] + bb;
                if constexpr (POS) x += pos[((rbase + rr) & 511) * 512 + col];
                if constexpr (ACT) x = fmaxf(x, 0.f);
                long long ci = (long long)(rbase + rr) * ldc + col;
                if constexpr (CMODE == 0 || CMODE == 2) Cf[ci] = x;
                if constexpr (CMODE >= 1)               Cb[ci] = (bf16)x;
            }
        }
    }
}

// W [K][N] f32  ->  WT [N][K] bf16   (32x32 LDS tiles)
__global__ __launch_bounds__(256)
void wt_k(const float* __restrict__ W, bf16* __restrict__ WT, int K, int N)
{
    __shared__ float t[32][33];
    int n0 = blockIdx.x * 32, k0 = blockIdx.y * 32;
    int r = threadIdx.x >> 3, c4 = (threadIdx.x & 7) * 4;
    float4 v = *(const float4*)&W[(long long)(k0 + r) * N + n0 + c4];
    t[r][c4 + 0] = v.x; t[r][c4 + 1] = v.y;
    t[r][c4 + 2] = v.z; t[r][c4 + 3] = v.w;
    __syncthreads();
    int n = threadIdx.x >> 3, kk4 = (threadIdx.x & 7) * 4;
    bf16x4 o;
    o[0] = (bf16)t[kk4 + 0][n]; o[1] = (bf16)t[kk4 + 1][n];
    o[2] = (bf16)t[kk4 + 2][n]; o[3] = (bf16)t[kk4 + 3][n];
    *(bf16x4*)&WT[(long long)(n0 + n) * K + k0 + kk4] = o;
}

// pack bq|bk|bv -> qkvB[2][1536]
__global__ __launch_bounds__(512)
void packb_k(const float* __restrict__ bq, const float* __restrict__ bk,
             const float* __restrict__ bv, float* __restrict__ dst)
{
    int l = blockIdx.x, t = threadIdx.x;
    dst[l * 1536 + t]        = bq[l * 512 + t];
    dst[l * 1536 + 512 + t]  = bk[l * 512 + t];
    dst[l * 1536 + 1024 + t] = bv[l * 512 + t];
}

// VT[h][d][s] = qkv[s][1024 + h*64 + d]   (bf16 64x64 LDS transpose)
__global__ __launch_bounds__(256)
void vt_k(const bf16* __restrict__ qkv, bf16* __restrict__ VT)
{
    __shared__ bf16 t[64][80];
    int h = blockIdx.y, s0 = blockIdx.x * 64;
    int r = threadIdx.x >> 2, c16 = (threadIdx.x & 3) * 16;
    const bf16* src = qkv + (long long)(s0 + r) * 1536 + 1024 + h * 64 + c16;
    *(bf16x8*)&t[r][c16]     = *(const bf16x8*)src;
    *(bf16x8*)&t[r][c16 + 8] = *(const bf16x8*)(src + 8);
    __syncthreads();
    int d = r, seg = c16;
    bf16 tmp[16];
    #pragma unroll
    for (int j = 0; j < 16; ++j) tmp[j] = t[seg + j][d];
    bf16* dst = VT + ((long long)(h * 64 + d)) * 512 + s0 + seg;
    *(bf16x8*)dst       = *(bf16x8*)&tmp[0];
    *(bf16x8*)(dst + 8) = *(bf16x8*)&tmp[8];
}

// masked-scale softmax: f32 scores in, bf16 probs out (full row incl. masked)
__global__ __launch_bounds__(256)
void softmax_k(const float* __restrict__ sc, bf16* __restrict__ pr)
{
    int row = blockIdx.x, h = blockIdx.y;
    const float* p = sc + ((long long)(h * SEQ + row)) * SEQ;
    bf16* o = pr + ((long long)(h * SEQ + row)) * SEQ;
    int tid = threadIdx.x;
    int j1 = tid + 256;
    float v0 = 0.f, v1 = 0.f;
    if (tid <= row) v0 = p[tid] * 0.125f;
    if (j1  <= row) v1 = p[j1]  * 0.125f;
    float m = fmaxf(v0, v1);
    #pragma unroll
    for (int off = 32; off; off >>= 1) m = fmaxf(m, __shfl_xor(m, off));
    __shared__ float red[4];
    if ((tid & 63) == 0) red[tid >> 6] = m;
    __syncthreads();
    m = fmaxf(fmaxf(red[0], red[1]), fmaxf(red[2], red[3]));
    float e0 = __expf(v0 - m);
    float e1 = __expf(v1 - m);
    float s = e0 + e1;
    #pragma unroll
    for (int off = 32; off; off >>= 1) s += __shfl_xor(s, off);
    __syncthreads();
    if ((tid & 63) == 0) red[tid >> 6] = s;
    __syncthreads();
    s = red[0] + red[1] + red[2] + red[3];
    float inv = 1.f / s;
    o[tid] = (bf16)(e0 * inv);
    o[j1]  = (bf16)(e1 * inv);
}

// x[row] = LN(x[row] + res[row & mask]) ; writes f32 x and bf16 xb
__global__ __launch_bounds__(128)
void addln_k(float* __restrict__ x, bf16* __restrict__ xb,
             const float* __restrict__ res, unsigned resMask,
             const float* __restrict__ g, const float* __restrict__ bta)
{
    long long row = blockIdx.x;
    int tid = threadIdx.x;
    int c = tid * 4;
    float4 xv = *(float4*)&x[row * 512 + c];
    float4 rv = *(const float4*)&res[(long long)(blockIdx.x & resMask) * 512 + c];
    xv.x += rv.x; xv.y += rv.y; xv.z += rv.z; xv.w += rv.w;
    float s = xv.x + xv.y + xv.z + xv.w;
    float q = xv.x * xv.x + xv.y * xv.y + xv.z * xv.z + xv.w * xv.w;
    #pragma unroll
    for (int off = 32; off; off >>= 1) {
        s += __shfl_xor(s, off);
        q += __shfl_xor(q, off);
    }
    __shared__ float rs[2], rq[2];
    if ((tid & 63) == 0) { rs[tid >> 6] = s; rq[tid >> 6] = q; }
    __syncthreads();
    s = rs[0] + rs[1]; q = rq[0] + rq[1];
    float mean = s * (1.0f / 512.0f);
    float var  = q * (1.0f / 512.0f) - mean * mean;
    float rstd = rsqrtf(var + 1e-5f);
    float4 gv = *(const float4*)&g[c];
    float4 bv = *(const float4*)&bta[c];
    float4 o;
    o.x = (xv.x - mean) * rstd * gv.x + bv.x;
    o.y = (xv.y - mean) * rstd * gv.y + bv.y;
    o.z = (xv.z - mean) * rstd * gv.z + bv.z;
    o.w = (xv.w - mean) * rstd * gv.w + bv.w;
    *(float4*)&x[row * 512 + c] = o;
    bf16* xo = xb + row * 512 + c;
    xo[0] = (bf16)o.x; xo[1] = (bf16)o.y; xo[2] = (bf16)o.z; xo[3] = (bf16)o.w;
}

// out[row] = dot(x[row,:], fcW) + fcb
__global__ __launch_bounds__(256)
void fc_k(const float* __restrict__ x, const float* __restrict__ w,
          const float* __restrict__ bb, float* __restrict__ out)
{
    int row  = blockIdx.x * 4 + (threadIdx.x >> 6);
    int lane = threadIdx.x & 63;
    const float* xr = x + (long long)row * 512;
    float4 a0 = *(const float4*)&xr[lane * 8];
    float4 a1 = *(const float4*)&xr[lane * 8 + 4];
    float4 w0 = *(const float4*)&w[lane * 8];
    float4 w1 = *(const float4*)&w[lane * 8 + 4];
    float s = a0.x * w0.x + a0.y * w0.y + a0.z * w0.z + a0.w * w0.w
            + a1.x * w1.x + a1.y * w1.y + a1.z * w1.z + a1.w * w1.w;
    #pragma unroll
    for (int off = 32; off; off >>= 1) s += __shfl_xor(s, off);
    if (lane == 0) out[row] = s + bb[0];
}

extern "C" void kernel_launch(void* const* d_in, const int* in_sizes, int n_in,
                              void* d_out, int out_size, void* d_ws, size_t ws_size,
                              hipStream_t stream)
{
    const float* input_seq = (const float*)d_in[0];
    const float* emb_W  = (const float*)d_in[1];
    const float* emb_b  = (const float*)d_in[2];
    const float* pos_emb= (const float*)d_in[3];
    const float* Wq = (const float*)d_in[4];
    const float* bq = (const float*)d_in[5];
    const float* Wk = (const float*)d_in[6];
    const float* bk = (const float*)d_in[7];
    const float* Wv = (const float*)d_in[8];
    const float* bv = (const float*)d_in[9];
    const float* Wo = (const float*)d_in[10];
    const float* bo = (const float*)d_in[11];
    const float* ln1_g = (const float*)d_in[12];
    const float* ln1_b = (const float*)d_in[13];
    const float* W1 = (const float*)d_in[14];
    const float* b1 = (const float*)d_in[15];
    const float* W2 = (const float*)d_in[16];
    const float* b2 = (const float*)d_in[17];
    const float* ln2_g = (const float*)d_in[18];
    const float* ln2_b = (const float*)d_in[19];
    const float* fcW = (const float*)d_in[20];
    const float* fcb = (const float*)d_in[21];
    float* out = (float*)d_out;

    // ---- workspace layout ----
    char* w = (char*)d_ws;
    size_t off = 0;
    auto alloc = [&](size_t b) -> void* {
        off = (off + 255) & ~(size_t)255;
        void* p = w + off;
        off += b;
        return p;
    };
    float* xbuf   = (float*)alloc(16384ull * 512 * 4);   // 32 MB
    bf16*  xb     = (bf16*) alloc(16384ull * 512 * 2);   // 16 MB
    bf16*  embWT  = (bf16*) alloc(512ull * 2048 * 2);
    bf16*  qkvWT  = (bf16*) alloc(2ull * 1536 * 512 * 2);
    bf16*  WoT    = (bf16*) alloc(2ull * 512 * 512 * 2);
    bf16*  W1T    = (bf16*) alloc(2ull * 2048 * 512 * 2);
    bf16*  W2T    = (bf16*) alloc(2ull * 512 * 2048 * 2);
    float* qkvB   = (float*)alloc(2ull * 1536 * 4);
    off = (off + 255) & ~(size_t)255;
    size_t dyn0 = off;
    char* dynp = w + dyn0;
    // attention overlay (16.25 MB)
    bf16*  qkv      = (bf16*)dynp;                         // 512x1536
    float* scores   = (float*)(dynp + 1572864);            // 8x512x512 f32
    bf16*  probs    = (bf16*)(dynp + 1572864 + 8388608);   // 8x512x512 bf16
    bf16*  VT       = (bf16*)(dynp + 1572864 + 8388608 + 4194304);
    bf16*  attn0b   = (bf16*)(dynp + 1572864 + 8388608 + 4194304 + 524288);
    float* attnout0 = (float*)(dynp + 1572864 + 8388608 + 4194304 + 524288 + 524288);
    // FFN overlay (same region): hidden bf16 [R][2048] + ffout f32 [R][512]
    size_t dynbytes = ws_size > dyn0 ? ws_size - dyn0 : 0;
    long long Rll = (long long)(dynbytes / 6144) & ~127ll;
    int R = (int)(Rll > 16384 ? 16384 : Rll);
    if (R < 128) R = 128;
    bf16*  hidden = (bf16*)dynp;
    float* ffout  = (float*)(dynp + (size_t)R * 4096);

    dim3 blk(256);

    // ---- weight conversion (transposed bf16) ----
    wt_k<<<dim3(16, 64), blk, 0, stream>>>(emb_W, embWT, 2048, 512);
    for (int l = 0; l < 2; ++l) {
        wt_k<<<dim3(16, 16), blk, 0, stream>>>(Wq + l * 262144, qkvWT + l * 786432,          512, 512);
        wt_k<<<dim3(16, 16), blk, 0, stream>>>(Wk + l * 262144, qkvWT + l * 786432 + 262144, 512, 512);
        wt_k<<<dim3(16, 16), blk, 0, stream>>>(Wv + l * 262144, qkvWT + l * 786432 + 524288, 512, 512);
        wt_k<<<dim3(16, 16), blk, 0, stream>>>(Wo + l * 262144, WoT + l * 262144, 512, 512);
        wt_k<<<dim3(64, 16), blk, 0, stream>>>(W1 + l * 1048576, W1T + l * 1048576, 512, 2048);
        wt_k<<<dim3(16, 64), blk, 0, stream>>>(W2 + l * 1048576, W2T + l * 1048576, 2048, 512);
    }
    packb_k<<<dim3(2), dim3(512), 0, stream>>>(bq, bk, bv, qkvB);

    // ---- embedding: x = input_seq @ emb_W + emb_b + pos_emb ; dual-write ----
    mgemm<128, 128, 0, 2, 1, 1, 0><<<dim3(4, 128), blk, 0, stream>>>(
        input_seq, 2048, 0, embWT, 2048, 0, emb_b, pos_emb,
        xbuf, xb, 512, 0, 2048);

    for (int l = 0; l < 2; ++l) {
        const bf16* qkvWT_l = qkvWT + l * 786432;
        const bf16* WoT_l   = WoT + l * 262144;
        const bf16* W1T_l   = W1T + l * 1048576;
        const bf16* W2T_l   = W2T + l * 1048576;

        // QKV projection (batch 0 rows only), packed N=1536, bf16 out
        mgemm<128, 128, 0, 1, 0, 0, 0><<<dim3(12, 4), blk, 0, stream>>>(
            xb, 512, 0, qkvWT_l, 512, 0, qkvB + l * 1536, nullptr,
            nullptr, qkv, 1536, 0, 512);
        // scores[h] = Qh @ Kh^T (causal tile skip), f32 out
        mgemm<128, 128, 0, 0, 0, 0, 1><<<dim3(4, 4, 8), blk, 0, stream>>>(
            qkv, 1536, 64, qkv + 512, 1536, 64, nullptr, nullptr,
            scores, nullptr, 512, 262144, 64);
        softmax_k<<<dim3(512, 8), blk, 0, stream>>>(scores, probs);
        vt_k<<<dim3(8, 8), blk, 0, stream>>>(qkv, VT);
        // attn0 = probs @ V (per head, N=64), bf16 out
        mgemm<128, 64, 0, 1, 0, 0, 0><<<dim3(1, 4, 8), blk, 0, stream>>>(
            probs, 512, 262144, VT, 512, 32768, nullptr, nullptr,
            nullptr, attn0b, 512, 64, 512);
        // attnout0 = attn0 @ Wo + bo, f32 out
        mgemm<128, 128, 0, 0, 0, 0, 0><<<dim3(4, 4), blk, 0, stream>>>(
            attn0b, 512, 0, WoT_l, 512, 0, bo + l * 512, nullptr,
            attnout0, nullptr, 512, 0, 512);
        // x = LN1(x + attnout0[s]) broadcast
        addln_k<<<dim3(16384), dim3(128), 0, stream>>>(
            xbuf, xb, attnout0, 511u, ln1_g + l * 512, ln1_b + l * 512);

        // ---- FFN, chunked by R rows ----
        for (int r0 = 0; r0 < 16384; r0 += R) {
            int Mc = 16384 - r0 < R ? 16384 - r0 : R;
            mgemm<128, 128, 1, 1, 0, 0, 0><<<dim3(16, Mc / 128), blk, 0, stream>>>(
                xb + (long long)r0 * 512, 512, 0, W1T_l, 512, 0, b1 + l * 2048,
                nullptr, nullptr, hidden, 2048, 0, 512);
            if ((Mc / 128) * 4 >= 224) {
                mgemm<128, 128, 0, 0, 0, 0, 0><<<dim3(4, Mc / 128), blk, 0, stream>>>(
                    hidden, 2048, 0, W2T_l, 2048, 0, b2 + l * 512, nullptr,
                    ffout, nullptr, 512, 0, 2048);
            } else {
                mgemm<128, 64, 0, 0, 0, 0, 0><<<dim3(8, Mc / 128), blk, 0, stream>>>(
                    hidden, 2048, 0, W2T_l, 2048, 0, b2 + l * 512, nullptr,
                    ffout, nullptr, 512, 0, 2048);
            }
            addln_k<<<dim3(Mc), dim3(128), 0, stream>>>(
                xbuf + (long long)r0 * 512, xb + (long long)r0 * 512, ffout,
                0xffffffffu, ln2_g + l * 512, ln2_b + l * 512);
        }
    }

    // ---- out = x @ fc_W + fc_b ----
    fc_k<<<dim3(4096), blk, 0, stream>>>(xbuf, fcW, fcb, out);
}